// Round 2
// baseline (566.287 us; speedup 1.0000x reference)
//
#include <hip/hip_runtime.h>
#include <hip/hip_bf16.h>

// Problem: out[n,o] = x[n,:] . W[o,:] + bias[o] + scale * sum_r (x[n,:].la[a,r,:]) * lb[a,o,:][r]
//          where a = lora_mapping[n]-1 (skip if mapping==0).
// Strategy: fold LoRA into the GEMM K-dim. Build bf16 Xe[16384,2176], We[2048,2176]
//   Xe[:,0:2048]=bf16(x); Xe[n,2048+(a*16+r)] = bf16(scale * x[n].la[a,r])  (one-hot in a)
//   We[:,0:2048]=bf16(W); We[o,2048+(a*16+r)] = bf16(lb[a,o,r])
// Then out = Xe @ We^T + bias — a single uniform bf16 MFMA GEMM, K=2176=34*64.
//
// R1 post-mortem: prep_x was 154us, latency-bound (VALUBusy 16%, hbm 15%) —
// per-rank serialized FMA->shuffle chains. R2: 16 parallel accumulators +
// pipelined butterfly (independent chains), unrolled select for the epilogue.

#define D_IN   2048
#define D_OUT  2048
#define NTOK   16384
#define RANK   16
#define NADAPT 8
#define KEXT   2176          // 2048 + 8*16
#define BM     128
#define BN     128
#define BK     64

typedef __attribute__((ext_vector_type(8))) __bf16 bf16x8;
typedef __attribute__((ext_vector_type(4))) float  f32x4;

__device__ inline unsigned short f2bf(float f) {
    unsigned u = __builtin_bit_cast(unsigned, f);
    u += 0x7fffu + ((u >> 16) & 1u);      // round-to-nearest-even
    return (unsigned short)(u >> 16);
}

// ---------------------------------------------------------------------------
// prep_x: one wave per token. Reads x row once (float4, coalesced), writes the
// bf16 row of Xe, computes the 16 LoRA-A dot products in fp32 with 16
// INDEPENDENT accumulator chains, then a pipelined 6-level butterfly across
// all 16 ranks (96 independent shuffle+add pairs, no serialized chains).
// ---------------------------------------------------------------------------
__global__ void prep_x(const float4* __restrict__ x, const int* __restrict__ map,
                       const float4* __restrict__ lora_a, const float* __restrict__ scaling,
                       unsigned short* __restrict__ Xe) {
    int wave = threadIdx.x >> 6, lane = threadIdx.x & 63;
    int n = blockIdx.x * 4 + wave;                       // token id
    const float4* xr = x + (size_t)n * (D_IN / 4);
    unsigned short* xo = Xe + (size_t)n * KEXT;

    int aid = map[n];                                    // 0 = no adapter (wave-uniform branch)

    float4 xv[8];
#pragma unroll
    for (int j = 0; j < 8; ++j) {
        xv[j] = xr[j * 64 + lane];
        ushort4 s;
        s.x = f2bf(xv[j].x); s.y = f2bf(xv[j].y);
        s.z = f2bf(xv[j].z); s.w = f2bf(xv[j].w);
        *(ushort4*)(xo + (j * 64 + lane) * 4) = s;       // 8B coalesced store
    }

    float acc[RANK];
#pragma unroll
    for (int r = 0; r < RANK; ++r) acc[r] = 0.f;

    if (aid > 0) {
        float sc = scaling[aid - 1];
        const float4* lab = lora_a + (size_t)(aid - 1) * RANK * (D_IN / 4);
        // j outer, r inner: 16 independent FMA chains; lora_a loads (L2-hot,
        // 2 MB total) get hoisted/pipelined by the compiler.
#pragma unroll
        for (int j = 0; j < 8; ++j) {
            float4 xj = xv[j];
#pragma unroll
            for (int r = 0; r < RANK; ++r) {
                float4 lv = lab[r * (D_IN / 4) + j * 64 + lane];
                acc[r] += xj.x * lv.x + xj.y * lv.y + xj.z * lv.z + xj.w * lv.w;
            }
        }
        // butterfly: 6 levels x 16 ranks, all shuffles within a level independent
#pragma unroll
        for (int m = 32; m >= 1; m >>= 1) {
            float other[RANK];
#pragma unroll
            for (int r = 0; r < RANK; ++r) other[r] = __shfl_xor(acc[r], m, 64);
#pragma unroll
            for (int r = 0; r < RANK; ++r) acc[r] += other[r];
        }
#pragma unroll
        for (int r = 0; r < RANK; ++r) acc[r] *= sc;
    }

    // extension write: lane covers columns D_IN + 2*lane, +1. Select the two
    // rank values with an unrolled compile-time tree (no runtime reg indexing).
    int c0 = lane * 2;
    ushort2 e; e.x = 0; e.y = 0;
    if (aid > 0 && (c0 >> 4) == (aid - 1)) {
        int rsel = c0 & 15;                              // even, 0..14
        float v0 = 0.f, v1 = 0.f;
#pragma unroll
        for (int r = 0; r < RANK; r += 2) {
            if (rsel == r) { v0 = acc[r]; v1 = acc[r + 1]; }
        }
        e.x = f2bf(v0); e.y = f2bf(v1);
    }
    *(ushort2*)(xo + D_IN + c0) = e;
}

// ---------------------------------------------------------------------------
// prep_w: one wave per output row. bf16(W row) + lb extension.
// ---------------------------------------------------------------------------
__global__ void prep_w(const float4* __restrict__ w, const float* __restrict__ lora_b,
                       unsigned short* __restrict__ We) {
    int wave = threadIdx.x >> 6, lane = threadIdx.x & 63;
    int o = blockIdx.x * 4 + wave;
    const float4* wr = w + (size_t)o * (D_IN / 4);
    unsigned short* wo = We + (size_t)o * KEXT;
#pragma unroll
    for (int j = 0; j < 8; ++j) {
        float4 v = wr[j * 64 + lane];
        ushort4 s;
        s.x = f2bf(v.x); s.y = f2bf(v.y); s.z = f2bf(v.z); s.w = f2bf(v.w);
        *(ushort4*)(wo + (j * 64 + lane) * 4) = s;
    }
    int c0 = lane * 2;
    int a = c0 >> 4, r = c0 & 15;                        // r even
    const float* src = lora_b + ((size_t)a * D_OUT + o) * RANK + r;
    ushort2 e; e.x = f2bf(src[0]); e.y = f2bf(src[1]);
    *(ushort2*)(wo + D_IN + c0) = e;
}

// ---------------------------------------------------------------------------
// Main GEMM: out[M=16384, N=2048] = Xe @ We^T + bias.  m97 structure:
// 128x128 tile, BK=64, 4 waves in 2x2, each wave 64x64 via 4x4 of 16x16x32
// bf16 MFMA, global_load_lds width=16 staging, XOR-swizzled LDS k-chunks
// (swizzle applied on the global source address so the wave-uniform LDS
// destination stays contiguous — required by global_load_lds semantics).
// ---------------------------------------------------------------------------
__global__ void gemm_fused(const unsigned short* __restrict__ Xe,
                           const unsigned short* __restrict__ We,
                           const float* __restrict__ bias,
                           float* __restrict__ out) {
    __shared__ unsigned short As[BM * BK];               // [128][64] bf16, 16 KB
    __shared__ unsigned short Bs[BN * BK];

    int t = threadIdx.x;
    int lane = t & 63, wave = t >> 6;
    // supertile swizzle: groups of 8 row-tiles x 16 col-tiles for L2 locality
    int g = blockIdx.x;
    int group = g >> 7, within = g & 127;
    int bm = group * 8 + (within & 7);                   // 0..127
    int bn = within >> 3;                                // 0..15

    int wm = wave >> 1, wn = wave & 1;                   // 2x2 wave grid
    f32x4 acc[4][4] = {};

    for (int k0 = 0; k0 < KEXT; k0 += BK) {
        __syncthreads();                                 // prev compute done
#pragma unroll
        for (int c = 0; c < 4; ++c) {
            int linear = (wave * 4 + c) * 64 + lane;     // 16B-chunk id within tile
            int row = linear >> 3;                       // 0..127
            int kc  = linear & 7;                        // 16B chunk within row
            int gc  = kc ^ (row & 7);                    // fetch swizzled source chunk
            const unsigned short* ga = Xe + (size_t)(bm * BM + row) * KEXT + k0 + gc * 8;
            __builtin_amdgcn_global_load_lds(
                (const __attribute__((address_space(1))) unsigned int*)ga,
                (__attribute__((address_space(3))) unsigned int*)(As + (wave * 4 + c) * 512),
                16, 0, 0);
            const unsigned short* gb = We + (size_t)(bn * BN + row) * KEXT + k0 + gc * 8;
            __builtin_amdgcn_global_load_lds(
                (const __attribute__((address_space(1))) unsigned int*)gb,
                (__attribute__((address_space(3))) unsigned int*)(Bs + (wave * 4 + c) * 512),
                16, 0, 0);
        }
        __syncthreads();                                 // staging visible (compiler drains vmcnt)
#pragma unroll
        for (int ks = 0; ks < 2; ++ks) {                 // two K=32 steps per BK=64
            bf16x8 af[4], bfr[4];
            int gchunk = ks * 4 + (lane >> 4);
            int sw = gchunk ^ (lane & 7);                // row&7 == lane&7 for 16-aligned tiles
#pragma unroll
            for (int i = 0; i < 4; ++i) {
                int rowA = wm * 64 + i * 16 + (lane & 15);
                af[i]  = *(const bf16x8*)(As + rowA * BK + sw * 8);
                int rowB = wn * 64 + i * 16 + (lane & 15);
                bfr[i] = *(const bf16x8*)(Bs + rowB * BK + sw * 8);
            }
#pragma unroll
            for (int i = 0; i < 4; ++i)
#pragma unroll
                for (int j = 0; j < 4; ++j)
                    acc[i][j] = __builtin_amdgcn_mfma_f32_16x16x32_bf16(af[i], bfr[j], acc[i][j], 0, 0, 0);
        }
    }

    // epilogue: C/D layout col=lane&15, row=(lane>>4)*4+reg  [m89-verified]
    int colq = lane & 15, rq = lane >> 4;
#pragma unroll
    for (int j = 0; j < 4; ++j) {
        int col = bn * BN + wn * 64 + j * 16 + colq;
        float bv = bias[col];
#pragma unroll
        for (int i = 0; i < 4; ++i) {
            int row0 = bm * BM + wm * 64 + i * 16 + rq * 4;
#pragma unroll
            for (int r = 0; r < 4; ++r)
                out[(size_t)(row0 + r) * D_OUT + col] = acc[i][j][r] + bv;
        }
    }
}

extern "C" void kernel_launch(void* const* d_in, const int* in_sizes, int n_in,
                              void* d_out, int out_size, void* d_ws, size_t ws_size,
                              hipStream_t stream) {
    (void)in_sizes; (void)n_in; (void)out_size; (void)ws_size;
    const float* x       = (const float*)d_in[0];
    const int*   map     = (const int*)d_in[1];
    const float* weight  = (const float*)d_in[2];
    const float* bias    = (const float*)d_in[3];
    const float* lora_a  = (const float*)d_in[4];
    const float* lora_b  = (const float*)d_in[5];
    const float* scaling = (const float*)d_in[6];
    float* out = (float*)d_out;

    unsigned short* Xe = (unsigned short*)d_ws;                    // 16384*2176*2 = 71.3 MB
    unsigned short* We = Xe + (size_t)NTOK * KEXT;                 // + 8.9 MB (16B aligned)

    prep_x<<<NTOK / 4, 256, 0, stream>>>((const float4*)x, map, (const float4*)lora_a, scaling, Xe);
    prep_w<<<D_OUT / 4, 256, 0, stream>>>((const float4*)weight, lora_b, We);
    gemm_fused<<<(NTOK / BM) * (D_OUT / BN), 256, 0, stream>>>(Xe, We, bias, out);
}

// Round 3
// 456.137 us; speedup vs baseline: 1.2415x; 1.2415x over previous
//
#include <hip/hip_runtime.h>
#include <hip/hip_bf16.h>

// Problem: out[n,o] = x[n,:] . W[o,:] + bias[o] + scale * sum_r (x[n,:].la[a,r,:]) * lb[a,o,:][r]
//          where a = lora_mapping[n]-1 (skip if mapping==0).
// Strategy: fold LoRA into the GEMM K-dim. Build bf16 Xe[16384,2176], We[2048,2176]
//   Xe[:,0:2048]=bf16(x); Xe[n,2048+(a*16+r)] = bf16(scale * x[n].la[a,r])  (one-hot in a)
//   We[:,0:2048]=bf16(W); We[o,2048+(a*16+r)] = bf16(lb[a,o,r])
// Then out = Xe @ We^T + bias — a single uniform bf16 MFMA GEMM, K=2176=34*64.
//
// R1: prep_x scalar+shuffle version latency-bound (154us).
// R2 FAILED: 16 parallel accumulators spilled to scratch (FETCH +139MB,
//   WRITE +245MB of spill traffic) -> 231us. Register pressure, not ILP.
// R3: compute u via MFMA for ALL adapters (x @ La_all^T, 128 cols), mask in
//   epilogue. No LDS, no shuffles, acc=8 VGPRs. Streaming-bound ~40us.

#define D_IN   2048
#define D_OUT  2048
#define NTOK   16384
#define RANK   16
#define NADAPT 8
#define KEXT   2176          // 2048 + 8*16
#define BM     128
#define BN     128
#define BK     64

typedef __attribute__((ext_vector_type(8))) __bf16 bf16x8;
typedef __attribute__((ext_vector_type(8))) unsigned short u16x8;
typedef __attribute__((ext_vector_type(4))) float  f32x4;

__device__ inline unsigned short f2bf(float f) {
    unsigned u = __builtin_bit_cast(unsigned, f);
    u += 0x7fffu + ((u >> 16) & 1u);      // round-to-nearest-even
    return (unsigned short)(u >> 16);
}

// ---------------------------------------------------------------------------
// conv_la: lora_a [8][16][2048] fp32 -> La [128][2048] bf16 (512 KB, L2-hot).
// Pure streaming convert, 65536 float4s.
// ---------------------------------------------------------------------------
__global__ void conv_la(const float4* __restrict__ la, ushort4* __restrict__ La) {
    int t = blockIdx.x * 256 + threadIdx.x;
    float4 v = la[t];
    ushort4 s;
    s.x = f2bf(v.x); s.y = f2bf(v.y); s.z = f2bf(v.z); s.w = f2bf(v.w);
    La[t] = s;
}

// ---------------------------------------------------------------------------
// prep_x_mfma: 16 tokens per block (grid 1024, 4 waves, no LDS).
// K-loop per 32: (a) coalesced fp32->bf16 convert+store of Xe[16 rows, k32],
// (b) A-frag direct from global x (fp32->bf16 in regs; all 4 waves load the
// same addresses -> L1 hits), (c) B-frags from L2-hot La, (d) 2 MFMAs/wave
// (wave w owns output cols w*32..w*32+31). Epilogue: mask u by the token's
// adapter id, scale, write the 128-wide extension (zeros elsewhere).
// u[token][c] = sum_k x[token,k]*La[c,k]; C-layout col=lane&15,
// row=(lane>>4)*4+reg  [m89-verified].
// ---------------------------------------------------------------------------
__global__ void prep_x_mfma(const float* __restrict__ x, const int* __restrict__ map,
                            const unsigned short* __restrict__ La,
                            const float* __restrict__ scaling,
                            unsigned short* __restrict__ Xe) {
    int t = threadIdx.x, lane = t & 63, wave = t >> 6;
    int n0 = blockIdx.x * 16;
    // conversion-pass ids: 256 threads cover a 16-row x 32-col fp32 chunk
    int crow = t >> 4;                    // 0..15
    int ckc  = t & 15;                    // float2 chunk (2 cols) within k32
    // fragment ids
    int arow = lane & 15;                 // A row (token) / B row (ext col)
    int kq   = lane >> 4;                 // 0..3 -> k offset kq*8

    f32x4 acc[2] = {};                    // 2 N-tiles of 16 cols each

    const float* xrow_c = x + (size_t)(n0 + crow) * D_IN + ckc * 2;
    unsigned short* xo_c = Xe + (size_t)(n0 + crow) * KEXT + ckc * 2;
    const float* xrow_a = x + (size_t)(n0 + arow) * D_IN + kq * 8;
    const unsigned short* lb0 = La + (size_t)(wave * 32 + arow) * D_IN + kq * 8;
    const unsigned short* lb1 = lb0 + (size_t)16 * D_IN;

    for (int k0 = 0; k0 < D_IN; k0 += 32) {
        // (a) streaming conversion + Xe store (coalesced)
        float2 cv = *(const float2*)(xrow_c + k0);
        ushort2 cs; cs.x = f2bf(cv.x); cs.y = f2bf(cv.y);
        *(ushort2*)(xo_c + k0) = cs;
        // (b) A fragment from global fp32 (L1-hot across waves)
        float4 a0 = *(const float4*)(xrow_a + k0);
        float4 a1 = *(const float4*)(xrow_a + k0 + 4);
        u16x8 au;
        au[0] = f2bf(a0.x); au[1] = f2bf(a0.y); au[2] = f2bf(a0.z); au[3] = f2bf(a0.w);
        au[4] = f2bf(a1.x); au[5] = f2bf(a1.y); au[6] = f2bf(a1.z); au[7] = f2bf(a1.w);
        bf16x8 af = __builtin_bit_cast(bf16x8, au);
        // (c) B fragments from L2-hot La (bf16, no conversion)
        bf16x8 b0 = *(const bf16x8*)(lb0 + k0);
        bf16x8 b1 = *(const bf16x8*)(lb1 + k0);
        // (d) accumulate
        acc[0] = __builtin_amdgcn_mfma_f32_16x16x32_bf16(af, b0, acc[0], 0, 0, 0);
        acc[1] = __builtin_amdgcn_mfma_f32_16x16x32_bf16(af, b1, acc[1], 0, 0, 0);
    }

    // epilogue: mask by adapter id, scale, write extension columns
    int aid_m[4];
#pragma unroll
    for (int r = 0; r < 4; ++r) aid_m[r] = map[n0 + kq * 4 + r];
#pragma unroll
    for (int j = 0; j < 2; ++j) {
        int c = wave * 32 + j * 16 + arow;          // extension col 0..127
        int a = c >> 4;                             // adapter of this col
        float sc = scaling[a];
#pragma unroll
        for (int r = 0; r < 4; ++r) {
            int token = n0 + kq * 4 + r;
            unsigned short v = 0;
            if (aid_m[r] == a + 1) v = f2bf(acc[j][r] * sc);
            Xe[(size_t)token * KEXT + D_IN + c] = v;
        }
    }
}

// ---------------------------------------------------------------------------
// prep_w: one wave per output row. bf16(W row) + lb extension.
// ---------------------------------------------------------------------------
__global__ void prep_w(const float4* __restrict__ w, const float* __restrict__ lora_b,
                       unsigned short* __restrict__ We) {
    int wave = threadIdx.x >> 6, lane = threadIdx.x & 63;
    int o = blockIdx.x * 4 + wave;
    const float4* wr = w + (size_t)o * (D_IN / 4);
    unsigned short* wo = We + (size_t)o * KEXT;
#pragma unroll
    for (int j = 0; j < 8; ++j) {
        float4 v = wr[j * 64 + lane];
        ushort4 s;
        s.x = f2bf(v.x); s.y = f2bf(v.y); s.z = f2bf(v.z); s.w = f2bf(v.w);
        *(ushort4*)(wo + (j * 64 + lane) * 4) = s;
    }
    int c0 = lane * 2;
    int a = c0 >> 4, r = c0 & 15;                        // r even
    const float* src = lora_b + ((size_t)a * D_OUT + o) * RANK + r;
    ushort2 e; e.x = f2bf(src[0]); e.y = f2bf(src[1]);
    *(ushort2*)(wo + D_IN + c0) = e;
}

// ---------------------------------------------------------------------------
// Main GEMM: out[M=16384, N=2048] = Xe @ We^T + bias.  m97 structure:
// 128x128 tile, BK=64, 4 waves in 2x2, each wave 64x64 via 4x4 of 16x16x32
// bf16 MFMA, global_load_lds width=16 staging, XOR-swizzled LDS k-chunks
// (swizzle applied on the global source address so the wave-uniform LDS
// destination stays contiguous — required by global_load_lds semantics).
// ---------------------------------------------------------------------------
__global__ void gemm_fused(const unsigned short* __restrict__ Xe,
                           const unsigned short* __restrict__ We,
                           const float* __restrict__ bias,
                           float* __restrict__ out) {
    __shared__ unsigned short As[BM * BK];               // [128][64] bf16, 16 KB
    __shared__ unsigned short Bs[BN * BK];

    int t = threadIdx.x;
    int lane = t & 63, wave = t >> 6;
    // supertile swizzle: groups of 8 row-tiles x 16 col-tiles for L2 locality
    int g = blockIdx.x;
    int group = g >> 7, within = g & 127;
    int bm = group * 8 + (within & 7);                   // 0..127
    int bn = within >> 3;                                // 0..15

    int wm = wave >> 1, wn = wave & 1;                   // 2x2 wave grid
    f32x4 acc[4][4] = {};

    for (int k0 = 0; k0 < KEXT; k0 += BK) {
        __syncthreads();                                 // prev compute done
#pragma unroll
        for (int c = 0; c < 4; ++c) {
            int linear = (wave * 4 + c) * 64 + lane;     // 16B-chunk id within tile
            int row = linear >> 3;                       // 0..127
            int kc  = linear & 7;                        // 16B chunk within row
            int gc  = kc ^ (row & 7);                    // fetch swizzled source chunk
            const unsigned short* ga = Xe + (size_t)(bm * BM + row) * KEXT + k0 + gc * 8;
            __builtin_amdgcn_global_load_lds(
                (const __attribute__((address_space(1))) unsigned int*)ga,
                (__attribute__((address_space(3))) unsigned int*)(As + (wave * 4 + c) * 512),
                16, 0, 0);
            const unsigned short* gb = We + (size_t)(bn * BN + row) * KEXT + k0 + gc * 8;
            __builtin_amdgcn_global_load_lds(
                (const __attribute__((address_space(1))) unsigned int*)gb,
                (__attribute__((address_space(3))) unsigned int*)(Bs + (wave * 4 + c) * 512),
                16, 0, 0);
        }
        __syncthreads();                                 // staging visible (compiler drains vmcnt)
#pragma unroll
        for (int ks = 0; ks < 2; ++ks) {                 // two K=32 steps per BK=64
            bf16x8 af[4], bfr[4];
            int gchunk = ks * 4 + (lane >> 4);
            int sw = gchunk ^ (lane & 7);                // row&7 == lane&7 for 16-aligned tiles
#pragma unroll
            for (int i = 0; i < 4; ++i) {
                int rowA = wm * 64 + i * 16 + (lane & 15);
                af[i]  = *(const bf16x8*)(As + rowA * BK + sw * 8);
                int rowB = wn * 64 + i * 16 + (lane & 15);
                bfr[i] = *(const bf16x8*)(Bs + rowB * BK + sw * 8);
            }
#pragma unroll
            for (int i = 0; i < 4; ++i)
#pragma unroll
                for (int j = 0; j < 4; ++j)
                    acc[i][j] = __builtin_amdgcn_mfma_f32_16x16x32_bf16(af[i], bfr[j], acc[i][j], 0, 0, 0);
        }
    }

    // epilogue: C/D layout col=lane&15, row=(lane>>4)*4+reg  [m89-verified]
    int colq = lane & 15, rq = lane >> 4;
#pragma unroll
    for (int j = 0; j < 4; ++j) {
        int col = bn * BN + wn * 64 + j * 16 + colq;
        float bv = bias[col];
#pragma unroll
        for (int i = 0; i < 4; ++i) {
            int row0 = bm * BM + wm * 64 + i * 16 + rq * 4;
#pragma unroll
            for (int r = 0; r < 4; ++r)
                out[(size_t)(row0 + r) * D_OUT + col] = acc[i][j][r] + bv;
        }
    }
}

extern "C" void kernel_launch(void* const* d_in, const int* in_sizes, int n_in,
                              void* d_out, int out_size, void* d_ws, size_t ws_size,
                              hipStream_t stream) {
    (void)in_sizes; (void)n_in; (void)out_size; (void)ws_size;
    const float* x       = (const float*)d_in[0];
    const int*   map     = (const int*)d_in[1];
    const float* weight  = (const float*)d_in[2];
    const float* bias    = (const float*)d_in[3];
    const float* lora_a  = (const float*)d_in[4];
    const float* lora_b  = (const float*)d_in[5];
    const float* scaling = (const float*)d_in[6];
    float* out = (float*)d_out;

    unsigned short* Xe = (unsigned short*)d_ws;                    // 16384*2176*2 = 71.3 MB
    unsigned short* We = Xe + (size_t)NTOK * KEXT;                 // + 8.9 MB
    unsigned short* La = We + (size_t)D_OUT * KEXT;                // + 0.5 MB bf16 [128][2048]

    conv_la<<<256, 256, 0, stream>>>((const float4*)lora_a, (ushort4*)La);
    prep_x_mfma<<<NTOK / 16, 256, 0, stream>>>(x, map, La, scaling, Xe);
    prep_w<<<D_OUT / 4, 256, 0, stream>>>((const float4*)weight, lora_b, We);
    gemm_fused<<<(NTOK / BM) * (D_OUT / BN), 256, 0, stream>>>(Xe, We, bias, out);
}